// Round 6
// baseline (125.454 us; speedup 1.0000x reference)
//
#include <hip/hip_runtime.h>
#include <hip/hip_bf16.h>

#define DIN  136
#define HH   128
#define NSEQ 256
#define NB   256
#define K1P  168          // padded K / w1t row stride in elements
#define S2   136          // h1 LDS row stride in elements

typedef __attribute__((ext_vector_type(4))) float f32x4;
typedef __attribute__((ext_vector_type(8))) short bf16x8;

static __device__ __forceinline__ unsigned short f2bf(float f) {
    unsigned int u = __float_as_uint(f);
    u += 0x7fffu + ((u >> 16) & 1u);          // round-to-nearest-even
    return (unsigned short)(u >> 16);
}

// ---------------------------------------------------------------------------
// Prep: bf16 W1^T [HH][K1P] (zero-padded K>=136) and W2^T [HH][HH], once.
// ---------------------------------------------------------------------------
__global__ __launch_bounds__(256)
void prep_kernel(const float* __restrict__ W1, const float* __restrict__ W2,
                 short* __restrict__ w1t, short* __restrict__ w2t)
{
    const int nt = gridDim.x * 256;
    const int idx = blockIdx.x * 256 + threadIdx.x;
    for (int e = idx; e < HH * K1P; e += nt) {
        const int n = e / K1P, k = e - n * K1P;
        w1t[e] = (k < DIN) ? (short)f2bf(W1[k * HH + n]) : (short)0;
    }
    for (int e = idx; e < HH * HH; e += nt) {
        const int n = e >> 7, k = e & 127;
        w2t[e] = (short)f2bf(W2[k * HH + n]);
    }
}

// ---------------------------------------------------------------------------
// Fused kernel v2: one block = one query (256 rows), 16 waves; wave wv owns
// rows [wv*16, wv*16+16) through both layers. Layer-1 A-fragments are loaded
// DIRECTLY from global fp32 (no LDS staging phase); h1 lives in LDS only as
// wave-private transpose scratch (no inter-layer barriers). LDS 76 KB ->
// 2 blocks/CU; launch_bounds(1024,8) targets <=64 VGPR for 32 waves/CU.
// ---------------------------------------------------------------------------
__global__ __launch_bounds__(1024, 8)
void fused_kernel(const float* __restrict__ features,
                  const int*   __restrict__ labels,
                  const short* __restrict__ w1t,
                  const short* __restrict__ w2t,
                  const float* __restrict__ b1, const float* __restrict__ b2,
                  const float* __restrict__ W3, const float* __restrict__ b3,
                  float* __restrict__ out)
{
    __shared__ short  h1[NSEQ * S2];       // 69632 B: h1 transpose scratch
    __shared__ float4 sp[NSEQ];            // 4 KB: per-row pack
    __shared__ float  s_part[4][NSEQ];     // 4 KB: lambda partials

    const int t    = threadIdx.x;
    const int lane = t & 63;
    const int wv   = t >> 6;      // 0..15: row-tile owner
    const int l15  = lane & 15;
    const int l4   = lane >> 4;
    const long row0 = (long)blockIdx.x * NSEQ;   // query = blockIdx.x

    // this lane's A row for both layers (global row for L1, LDS row for L2)
    const float* frow = features + (row0 + wv * 16 + l15) * (long)DIN;
    const int    arow = (wv * 16 + l15) * S2;

    // ---- layer 1: h1 = relu(A @ W1 + b1), K=136 (+pad), A direct-from-global
    f32x4 acc[8];
#pragma unroll
    for (int tn = 0; tn < 8; ++tn) {
        const float bv = b1[tn * 16 + l15];
        acc[tn] = (f32x4){bv, bv, bv, bv};
    }
    for (int kc = 0; kc < 5; ++kc) {
        const int kb = kc * 32 + l4 * 8;
        bf16x8 afr;
        if (kb < DIN) {    // kb+8 <= 136 holds whenever kb < 136
            const f32x4 g0 = *(const f32x4*)&frow[kb];
            const f32x4 g1 = *(const f32x4*)&frow[kb + 4];
            afr[0] = (short)f2bf(g0.x); afr[1] = (short)f2bf(g0.y);
            afr[2] = (short)f2bf(g0.z); afr[3] = (short)f2bf(g0.w);
            afr[4] = (short)f2bf(g1.x); afr[5] = (short)f2bf(g1.y);
            afr[6] = (short)f2bf(g1.z); afr[7] = (short)f2bf(g1.w);
        } else {
            afr = (bf16x8){0,0,0,0,0,0,0,0};   // w1t cols >=136 are zero too
        }
        bf16x8 bfr[4];
#pragma unroll
        for (int tn = 0; tn < 4; ++tn)
            bfr[tn] = *(const bf16x8*)&w1t[(tn * 16 + l15) * K1P + kb];
#pragma unroll
        for (int tn = 0; tn < 4; ++tn)
            acc[tn] = __builtin_amdgcn_mfma_f32_16x16x32_bf16(afr, bfr[tn], acc[tn], 0, 0, 0);
#pragma unroll
        for (int tn = 0; tn < 4; ++tn)
            bfr[tn] = *(const bf16x8*)&w1t[((tn + 4) * 16 + l15) * K1P + kb];
#pragma unroll
        for (int tn = 0; tn < 4; ++tn)
            acc[tn + 4] = __builtin_amdgcn_mfma_f32_16x16x32_bf16(afr, bfr[tn], acc[tn + 4], 0, 0, 0);
    }

    // ---- relu(h1) -> bf16 into the wave's OWN rows (same-wave DS ordering,
    //      no barrier).  C/D layout: row = l4*4+j, col = l15. ----
#pragma unroll
    for (int tn = 0; tn < 8; ++tn) {
        const int col = tn * 16 + l15;
#pragma unroll
        for (int j = 0; j < 4; ++j)
            h1[(wv * 16 + l4 * 4 + j) * S2 + col] =
                (short)f2bf(fmaxf(acc[tn][j], 0.f));
    }

    // ---- layer 2: h2 = relu(h1 @ W2 + b2), K = 128 ----
    f32x4 acc2[8];
#pragma unroll
    for (int tn = 0; tn < 8; ++tn) {
        const float bv = b2[tn * 16 + l15];
        acc2[tn] = (f32x4){bv, bv, bv, bv};
    }
    for (int kc = 0; kc < 4; ++kc) {
        const int kb = kc * 32 + l4 * 8;
        const bf16x8 afr = *(const bf16x8*)&h1[arow + kb];
        bf16x8 bfr[4];
#pragma unroll
        for (int tn = 0; tn < 4; ++tn)
            bfr[tn] = *(const bf16x8*)&w2t[(tn * 16 + l15) * HH + kb];
#pragma unroll
        for (int tn = 0; tn < 4; ++tn)
            acc2[tn] = __builtin_amdgcn_mfma_f32_16x16x32_bf16(afr, bfr[tn], acc2[tn], 0, 0, 0);
#pragma unroll
        for (int tn = 0; tn < 4; ++tn)
            bfr[tn] = *(const bf16x8*)&w2t[((tn + 4) * 16 + l15) * HH + kb];
#pragma unroll
        for (int tn = 0; tn < 4; ++tn)
            acc2[tn + 4] = __builtin_amdgcn_mfma_f32_16x16x32_bf16(afr, bfr[tn], acc2[tn + 4], 0, 0, 0);
    }

    // ---- layer 3 + per-row pack {s*log2e, 0.5*gain, disc} into LDS ----
    {
        float w3v[8];
#pragma unroll
        for (int tn = 0; tn < 8; ++tn) w3v[tn] = W3[tn * 16 + l15];
        const float b3v = b3[0];
#pragma unroll
        for (int j = 0; j < 4; ++j) {
            float p = 0.f;
#pragma unroll
            for (int tn = 0; tn < 8; ++tn)
                p += fmaxf(acc2[tn][j], 0.f) * w3v[tn];
            p += __shfl_xor(p, 1, 64);
            p += __shfl_xor(p, 2, 64);
            p += __shfl_xor(p, 4, 64);
            p += __shfl_xor(p, 8, 64);
            if (l15 == 0) {
                const int row = wv * 16 + l4 * 4 + j;
                const float s = p + b3v;
                const int lab = labels[row0 + row];
                const float g = 0.5f * exp2f((float)lab);      // 0.5 folded
                const float disc = 1.f / (1.f + log2f(1.f + s));
                sp[row] = make_float4(s * 1.44269504088896f,   // log2e folded
                                      g, disc, 0.f);
            }
        }
    }
    __syncthreads();

    // ---- pairwise lambdas: i = t&255, jg = t>>8 (64 j each) ----
    {
        const int i  = t & (NSEQ - 1);
        const int jg = t >> 8;
        const float4 me = sp[i];
        const float sci = me.x, gi = me.y, di = me.z;
        float accum = 0.f;
        const int j0 = jg * 64;
#pragma unroll 8
        for (int jj = 0; jj < 64; ++jj) {
            const float4 o = sp[j0 + jj];
            const float dg = o.y - gi;                         // (gj-gi)/2
            const float e  = exp2f(o.x - sci);                 // exp(sj-si)
            const float r  = __builtin_amdgcn_rcpf(1.f + e);   // sigmoid(si-sj)
            const float dmax = (sci > o.x) ? di : o.z;         // disc of max
            const float dn = fabsf(dg) * dmax;                 // 0 when li==lj
            const float w  = (dg < 0.f) ? r : (r - 1.f);
            accum += dn * w;
        }
        s_part[jg][i] = accum;
    }
    __syncthreads();
    {
        const int i = t & (NSEQ - 1);
        if ((t >> 8) == 0)
            out[row0 + i] = s_part[0][i] + s_part[1][i] +
                            s_part[2][i] + s_part[3][i];
    }
}

// ---------------------------------------------------------------------------
extern "C" void kernel_launch(void* const* d_in, const int* in_sizes, int n_in,
                              void* d_out, int out_size, void* d_ws, size_t ws_size,
                              hipStream_t stream)
{
    const float* features = (const float*)d_in[0];
    const int*   labels   = (const int*)d_in[1];
    const float* W1 = (const float*)d_in[2];
    const float* b1 = (const float*)d_in[3];
    const float* W2 = (const float*)d_in[4];
    const float* b2 = (const float*)d_in[5];
    const float* W3 = (const float*)d_in[6];
    const float* b3 = (const float*)d_in[7];

    short* w1t = (short*)d_ws;             // 128*168 bf16
    short* w2t = w1t + HH * K1P;           // 128*128 bf16
    float* out = (float*)d_out;

    prep_kernel<<<64, 256, 0, stream>>>(W1, W2, w1t, w2t);
    fused_kernel<<<NB, 1024, 0, stream>>>(
        features, labels, w1t, w2t, b1, b2, W3, b3, out);
}

// Round 7
// 106.010 us; speedup vs baseline: 1.1834x; 1.1834x over previous
//
#include <hip/hip_runtime.h>
#include <hip/hip_bf16.h>

#define DIN  136
#define HH   128
#define NSEQ 256
#define NB   256
#define ST   136          // uniform LDS row stride (elements); 272B -> 2-way banks (free)

typedef __attribute__((ext_vector_type(4))) float f32x4;
typedef __attribute__((ext_vector_type(8))) short bf16x8;

static __device__ __forceinline__ unsigned cvt2(float lo, float hi) {
    __hip_bfloat162 h = __float22bfloat162_rn(make_float2(lo, hi));
    return *(unsigned*)&h;
}
static __device__ __forceinline__ short f2bf1(float f) {
    __hip_bfloat16 h = __float2bfloat16(f);
    return *(short*)&h;
}

// ---------------------------------------------------------------------------
// Prep: weights in LDS-final layout. w1s[n][k] = bf16(W1[k][n]), [128][136];
// w2s[n][k] = bf16(W2[k][n]) for k<128 else 0, [128][136]. Contiguous so the
// fused kernel stages both with one linear 69.6 KB copy.
// ---------------------------------------------------------------------------
__global__ __launch_bounds__(256)
void prep_kernel(const float* __restrict__ W1, const float* __restrict__ W2,
                 short* __restrict__ w1s, short* __restrict__ w2s)
{
    const int nt = gridDim.x * 256;
    const int idx = blockIdx.x * 256 + threadIdx.x;
    for (int e = idx; e < HH * ST; e += nt) {
        const int n = e / ST, k = e - n * ST;          // k in [0,136) = real
        w1s[e] = f2bf1(W1[k * HH + n]);
    }
    for (int e = idx; e < HH * ST; e += nt) {
        const int n = e / ST, k = e - n * ST;
        w2s[e] = (k < HH) ? f2bf1(W2[k * HH + n]) : (short)0;
    }
}

// ---------------------------------------------------------------------------
// Fused kernel v3: one block = one query (256 rows), 16 waves. All MFMA
// operands come from LDS: weights staged once per block via linear coalesced
// copy; features staged bf16 [256][136]; h1 overwrites the wave's OWN feature
// rows (same-wave DS ordering -> no inter-layer barrier). K-tail (136=4*32+8)
// via an l4==0-masked 5th MFMA step. sp/s_part overlay a_lds post-barrier.
// LDS 136 KiB, 1 block/CU (grid == #CU).
// ---------------------------------------------------------------------------
__global__ __launch_bounds__(1024, 4)
void fused_kernel(const float* __restrict__ features,
                  const int*   __restrict__ labels,
                  const short* __restrict__ w1s,   // [128][136] bf16
                  const short* __restrict__ w2s,   // [128][136] bf16
                  const float* __restrict__ b1, const float* __restrict__ b2,
                  const float* __restrict__ W3, const float* __restrict__ b3,
                  float* __restrict__ out)
{
    __shared__ __align__(16) char smem[139264];
    short* a_lds  = (short*)smem;                  // [256][136] features -> h1
    short* w1_lds = (short*)(smem + 69632);        // [128][136]
    short* w2_lds = (short*)(smem + 104448);       // [128][136]
    float4* sp    = (float4*)smem;                 // overlay: per-row pack (4 KB)
    float (*s_part)[NSEQ] = (float (*)[NSEQ])(smem + 4096);   // overlay (4 KB)

    const int t    = threadIdx.x;
    const int lane = t & 63;
    const int wv   = t >> 6;      // 0..15: row-tile owner
    const int l15  = lane & 15;
    const int l4   = lane >> 4;
    const long row0 = (long)blockIdx.x * NSEQ;     // query = blockIdx.x

    // ---- stage weights: linear 69632 B = 4352 uint4 (w1s,w2s contiguous) ----
    {
        const uint4* src = (const uint4*)w1s;
        uint4* dst = (uint4*)w1_lds;
        for (int i = t; i < 2 * HH * ST / 8; i += 1024)
            dst[i] = src[i];
    }
    // ---- stage features fp32 -> bf16 (8704 f32x4; 34 per row) ----
    {
        const f32x4* src = (const f32x4*)(features + row0 * DIN);
        for (int i = t; i < NSEQ * DIN / 4; i += 1024) {
            const f32x4 v = src[i];
            const int r = i / 34, c = i - r * 34;
            uint2 p;
            p.x = cvt2(v.x, v.y);
            p.y = cvt2(v.z, v.w);
            *(uint2*)&a_lds[r * ST + c * 4] = p;
        }
    }
    __syncthreads();

    const int arow = (wv * 16 + l15) * ST;

    // ---- layer 1: h1 = relu(A @ W1 + b1), K = 4*32 + 8 tail ----
    f32x4 acc[8];
#pragma unroll
    for (int tn = 0; tn < 8; ++tn) {
        const float bv = b1[tn * 16 + l15];
        acc[tn] = (f32x4){bv, bv, bv, bv};
    }
    for (int kc = 0; kc < 4; ++kc) {
        const int kb = kc * 32 + l4 * 8;
        const bf16x8 afr = *(const bf16x8*)&a_lds[arow + kb];
        bf16x8 bfr[8];
#pragma unroll
        for (int tn = 0; tn < 8; ++tn)
            bfr[tn] = *(const bf16x8*)&w1_lds[(tn * 16 + l15) * ST + kb];
#pragma unroll
        for (int tn = 0; tn < 8; ++tn)
            acc[tn] = __builtin_amdgcn_mfma_f32_16x16x32_bf16(afr, bfr[tn], acc[tn], 0, 0, 0);
    }
    {   // K-tail: cols 128..136, contributed only by the l4==0 k-group
        bf16x8 afr = (bf16x8){0,0,0,0,0,0,0,0};
        bf16x8 bfr[8];
#pragma unroll
        for (int tn = 0; tn < 8; ++tn) bfr[tn] = (bf16x8){0,0,0,0,0,0,0,0};
        if (l4 == 0) {
            afr = *(const bf16x8*)&a_lds[arow + 128];
#pragma unroll
            for (int tn = 0; tn < 8; ++tn)
                bfr[tn] = *(const bf16x8*)&w1_lds[(tn * 16 + l15) * ST + 128];
        }
#pragma unroll
        for (int tn = 0; tn < 8; ++tn)
            acc[tn] = __builtin_amdgcn_mfma_f32_16x16x32_bf16(afr, bfr[tn], acc[tn], 0, 0, 0);
    }

    // ---- relu(h1) -> bf16 into the wave's OWN rows (no barrier needed).
    //      C/D layout: row = l4*4+j, col = l15  [m89/m91]. ----
#pragma unroll
    for (int tn = 0; tn < 8; ++tn) {
        const int col = tn * 16 + l15;
#pragma unroll
        for (int j = 0; j < 4; ++j)
            a_lds[(wv * 16 + l4 * 4 + j) * ST + col] = f2bf1(fmaxf(acc[tn][j], 0.f));
    }

    // ---- layer 2: h2 = relu(h1 @ W2 + b2), K = 128 ----
    f32x4 acc2[8];
#pragma unroll
    for (int tn = 0; tn < 8; ++tn) {
        const float bv = b2[tn * 16 + l15];
        acc2[tn] = (f32x4){bv, bv, bv, bv};
    }
    for (int kc = 0; kc < 4; ++kc) {
        const int kb = kc * 32 + l4 * 8;
        const bf16x8 afr = *(const bf16x8*)&a_lds[arow + kb];
        bf16x8 bfr[8];
#pragma unroll
        for (int tn = 0; tn < 8; ++tn)
            bfr[tn] = *(const bf16x8*)&w2_lds[(tn * 16 + l15) * ST + kb];
#pragma unroll
        for (int tn = 0; tn < 8; ++tn)
            acc2[tn] = __builtin_amdgcn_mfma_f32_16x16x32_bf16(afr, bfr[tn], acc2[tn], 0, 0, 0);
    }
    __syncthreads();   // all a_lds/w_lds reads done before sp/s_part overlay

    // ---- layer 3 + per-row pack {s*log2e, 0.5*gain, disc} into sp ----
    {
        float w3v[8];
#pragma unroll
        for (int tn = 0; tn < 8; ++tn) w3v[tn] = W3[tn * 16 + l15];
        const float b3v = b3[0];
#pragma unroll
        for (int j = 0; j < 4; ++j) {
            float p = 0.f;
#pragma unroll
            for (int tn = 0; tn < 8; ++tn)
                p += fmaxf(acc2[tn][j], 0.f) * w3v[tn];
            p += __shfl_xor(p, 1, 64);
            p += __shfl_xor(p, 2, 64);
            p += __shfl_xor(p, 4, 64);
            p += __shfl_xor(p, 8, 64);
            if (l15 == 0) {
                const int row = wv * 16 + l4 * 4 + j;
                const float s = p + b3v;
                const int lab = labels[row0 + row];
                const float g = 0.5f * exp2f((float)lab);      // 0.5 folded
                const float disc = 1.f / (1.f + log2f(1.f + s));
                sp[row] = make_float4(s * 1.44269504088896f,   // log2e folded
                                      g, disc, 0.f);
            }
        }
    }
    __syncthreads();

    // ---- pairwise lambdas: i = t&255, jg = t>>8 (64 j each) ----
    {
        const int i  = t & (NSEQ - 1);
        const int jg = t >> 8;
        const float4 me = sp[i];
        const float sci = me.x, gi = me.y, di = me.z;
        float accum = 0.f;
        const int j0 = jg * 64;
#pragma unroll 8
        for (int jj = 0; jj < 64; ++jj) {
            const float4 o = sp[j0 + jj];
            const float dg = o.y - gi;                         // (gj-gi)/2
            const float e  = exp2f(o.x - sci);                 // exp(sj-si)
            const float r  = __builtin_amdgcn_rcpf(1.f + e);   // sigmoid(si-sj)
            const float dmax = (sci > o.x) ? di : o.z;         // disc of max
            const float dn = fabsf(dg) * dmax;                 // 0 when li==lj
            const float w  = (dg < 0.f) ? r : (r - 1.f);
            accum += dn * w;
        }
        s_part[jg][i] = accum;
    }
    __syncthreads();
    {
        const int i = t & (NSEQ - 1);
        if ((t >> 8) == 0)
            out[row0 + i] = s_part[0][i] + s_part[1][i] +
                            s_part[2][i] + s_part[3][i];
    }
}

// ---------------------------------------------------------------------------
extern "C" void kernel_launch(void* const* d_in, const int* in_sizes, int n_in,
                              void* d_out, int out_size, void* d_ws, size_t ws_size,
                              hipStream_t stream)
{
    const float* features = (const float*)d_in[0];
    const int*   labels   = (const int*)d_in[1];
    const float* W1 = (const float*)d_in[2];
    const float* b1 = (const float*)d_in[3];
    const float* W2 = (const float*)d_in[4];
    const float* b2 = (const float*)d_in[5];
    const float* W3 = (const float*)d_in[6];
    const float* b3 = (const float*)d_in[7];

    short* w1s = (short*)d_ws;             // [128][136] bf16
    short* w2s = w1s + HH * ST;            // [128][136] bf16 (contiguous)
    float* out = (float*)d_out;

    prep_kernel<<<64, 256, 0, stream>>>(W1, W2, w1s, w2s);
    fused_kernel<<<NB, 1024, 0, stream>>>(
        features, labels, w1s, w2s, b1, b2, W3, b3, out);
}